// Round 18
// baseline (1861.762 us; speedup 1.0000x reference)
//
#include <hip/hip_runtime.h>
#include <math.h>

typedef unsigned short ushort_t;
using bf16x8  = __attribute__((ext_vector_type(8))) short;
using f32x4   = __attribute__((ext_vector_type(4))) float;
using ushort8 = __attribute__((ext_vector_type(8))) unsigned short;

__device__ __forceinline__ unsigned short f2bf(float f) {
    union { float f; unsigned int u; } v; v.f = f;
    unsigned int r = v.u + 0x7FFFu + ((v.u >> 16) & 1u);   // RNE
    return (unsigned short)(r >> 16);
}
__device__ __forceinline__ float bf2f(unsigned short u) {
    union { unsigned int u; float f; } v; v.u = ((unsigned int)u) << 16;
    return v.f;
}

// ---- fp8 e4m3 (OCP) helpers: HW cvt when available, manual fallback ----
#if defined(__has_builtin)
#if __has_builtin(__builtin_amdgcn_cvt_f32_fp8) && __has_builtin(__builtin_amdgcn_cvt_pk_fp8_f32)
#define FP8_HW 1
#endif
#endif

__device__ __forceinline__ unsigned char f2fp8(float v) {
#ifdef FP8_HW
    unsigned int p = __builtin_amdgcn_cvt_pk_fp8_f32(v, v, 0, false);
    return (unsigned char)(p & 0xFFu);
#else
    union { float f; unsigned u; } b; b.f = v;
    unsigned s = (b.u >> 24) & 0x80u;
    float a = fabsf(v);
    if (a >= 448.f) return (unsigned char)(s | 0x7E);
    if (a < 0.015625f) {                      // subnormal: m = round(a * 512)
        int m = (int)rintf(a * 512.0f);
        if (m >= 8) return (unsigned char)(s | 0x08);
        return (unsigned char)(s | (unsigned)m);
    }
    unsigned u = b.u & 0x7FFFFFFFu;
    u += 0x7FFFFu + ((u >> 20) & 1u);        // RNE at mantissa bit 20
    int e8 = (int)((u >> 23) & 0xFF) - 120;
    unsigned M = (u >> 20) & 7u;
    if (e8 > 15 || (e8 == 15 && M == 7u)) return (unsigned char)(s | 0x7E);
    return (unsigned char)(s | ((unsigned)e8 << 3) | M);
#endif
}

#ifdef FP8_HW
#define ACC8(ac, w) do { \
    ac[0] += __builtin_amdgcn_cvt_f32_fp8((int)(w).x, 0); \
    ac[1] += __builtin_amdgcn_cvt_f32_fp8((int)(w).x, 1); \
    ac[2] += __builtin_amdgcn_cvt_f32_fp8((int)(w).x, 2); \
    ac[3] += __builtin_amdgcn_cvt_f32_fp8((int)(w).x, 3); \
    ac[4] += __builtin_amdgcn_cvt_f32_fp8((int)(w).y, 0); \
    ac[5] += __builtin_amdgcn_cvt_f32_fp8((int)(w).y, 1); \
    ac[6] += __builtin_amdgcn_cvt_f32_fp8((int)(w).y, 2); \
    ac[7] += __builtin_amdgcn_cvt_f32_fp8((int)(w).y, 3); \
} while (0)
#else
__device__ __forceinline__ float fp82f(unsigned u) {
    unsigned s = u >> 7, e = (u >> 3) & 15u, m = u & 7u;
    union { unsigned u; float f; } nb;
    nb.u = (s << 31) | ((e + 120u) << 23) | (m << 20);
    float sub = (float)(int)m * 0.001953125f;
    sub = s ? -sub : sub;
    return e ? nb.f : sub;
}
#define ACC8(ac, w) do { \
    ac[0] += fp82f(((w).x      ) & 0xFFu); \
    ac[1] += fp82f(((w).x >>  8) & 0xFFu); \
    ac[2] += fp82f(((w).x >> 16) & 0xFFu); \
    ac[3] += fp82f(((w).x >> 24)        ); \
    ac[4] += fp82f(((w).y      ) & 0xFFu); \
    ac[5] += fp82f(((w).y >>  8) & 0xFFu); \
    ac[6] += fp82f(((w).y >> 16) & 0xFFu); \
    ac[7] += fp82f(((w).y >> 24)        ); \
} while (0)
#endif

typedef const __attribute__((address_space(1))) void* gas_ptr;
typedef __attribute__((address_space(3))) void* las_ptr;
__device__ __forceinline__ void gload16(const void* g, void* l) {
    __builtin_amdgcn_global_load_lds((gas_ptr)g, (las_ptr)l, 16, 0, 0);
}

// XCD-aware bijective swizzle (T1): dispatch index i -> logical col-fast tile id.
__device__ __forceinline__ void xcd_tile(int* col, int* row) {
    int nx = gridDim.x;
    int nwg = nx * gridDim.y;
    int i = blockIdx.y * nx + blockIdx.x;
    int l = i;
    if ((nwg & 7) == 0) {
        int cpx = nwg >> 3;
        l = (i & 7) * cpx + (i >> 3);
    }
    *col = l % nx;
    *row = l / nx;
}

// ---------------- CSR build ----------------

__global__ void k_zero_i32(int* __restrict__ p, int n) {
    int i = blockIdx.x * blockDim.x + threadIdx.x;
    if (i < n) p[i] = 0;
}

__global__ void k_count_deg(const int* __restrict__ erow, int* __restrict__ deg, int e) {
    for (int i = blockIdx.x * blockDim.x + threadIdx.x; i < e; i += gridDim.x * blockDim.x)
        atomicAdd(&deg[erow[i]], 1);
}

__global__ __launch_bounds__(1024) void k_scan(const int* __restrict__ deg, int* __restrict__ ptr,
                                               int* __restrict__ cursor, int n) {
    __shared__ int buf[1024];
    __shared__ int carry_s;
    int t = threadIdx.x;
    if (t == 0) { carry_s = 0; ptr[0] = 0; }
    __syncthreads();
    for (int base = 0; base < n; base += 1024) {
        int i = base + t;
        int v = (i < n) ? deg[i] : 0;
        buf[t] = v;
        __syncthreads();
        #pragma unroll
        for (int off = 1; off < 1024; off <<= 1) {
            int xv = (t >= off) ? buf[t - off] : 0;
            __syncthreads();
            buf[t] += xv;
            __syncthreads();
        }
        int carry = carry_s;
        int incl = buf[t] + carry;
        if (i < n) { ptr[i + 1] = incl; cursor[i] = incl - v; }
        int bsum = buf[1023];
        __syncthreads();
        if (t == 0) carry_s = carry + bsum;
        __syncthreads();
    }
}

__global__ void k_scatter(const int* __restrict__ erow, const int* __restrict__ ecol,
                          int* __restrict__ cursor, int* __restrict__ csr_col, int e) {
    for (int i = blockIdx.x * blockDim.x + threadIdx.x; i < e; i += gridDim.x * blockDim.x) {
        int pos = atomicAdd(&cursor[erow[i]], 1);
        csr_col[pos] = ecol[i];
    }
}

// ---------------- transpose + fp32->bf16: WT[n][kp] = bf16(W[kp][n]), kp>=K -> 0 ----------------

__global__ __launch_bounds__(256) void k_cvt_wT(const float* __restrict__ W, unsigned short* __restrict__ WT,
                                                int K, int N, int Kpad) {
    __shared__ float tile[32][33];
    int kp0 = blockIdx.x * 32, n0 = blockIdx.y * 32;
    int tx = threadIdx.x & 31, ty = threadIdx.x >> 5;   // 32 x 8
    #pragma unroll
    for (int ii = 0; ii < 4; ++ii) {
        int k = kp0 + ty + ii * 8;
        tile[ty + ii * 8][tx] = (k < K) ? W[(size_t)k * N + n0 + tx] : 0.0f;
    }
    __syncthreads();
    #pragma unroll
    for (int ii = 0; ii < 4; ++ii) {
        int n = n0 + ty + ii * 8;
        WT[(size_t)n * Kpad + kp0 + tx] = f2bf(tile[tx][ty + ii * 8]);
    }
}

// ---------------- SpMM1 (fp32 x): ax[i][:] = bf16( (1/deg_i) * sum x[col][:] ), out 320-wide ----------------

__global__ __launch_bounds__(128) void k_spmm1(const int* __restrict__ ptr, const int* __restrict__ col,
                                               const float* __restrict__ x, unsigned short* __restrict__ ax) {
    int r = blockIdx.x;
    int t = threadIdx.x;
    int s = ptr[r], e = ptr[r + 1];
    bool act = t < 75;
    const float4* xb = (const float4*)x;
    float4 a0 = {0.f, 0.f, 0.f, 0.f}, a1 = {0.f, 0.f, 0.f, 0.f};
    int p = s;
    for (; p + 1 < e; p += 2) {
        int c0 = col[p], c1 = col[p + 1];
        if (act) {
            float4 v0 = xb[(size_t)c0 * 75 + t];
            float4 v1 = xb[(size_t)c1 * 75 + t];
            a0.x += v0.x; a0.y += v0.y; a0.z += v0.z; a0.w += v0.w;
            a1.x += v1.x; a1.y += v1.y; a1.z += v1.z; a1.w += v1.w;
        }
    }
    if (p < e && act) {
        float4 v = xb[(size_t)col[p] * 75 + t];
        a0.x += v.x; a0.y += v.y; a0.z += v.z; a0.w += v.w;
    }
    float w = 1.0f / fmaxf((float)(e - s), 1.0f);
    unsigned short* o = ax + (size_t)r * 320;
    if (act) {
        ushort4 ov;
        ov.x = f2bf((a0.x + a1.x) * w);
        ov.y = f2bf((a0.y + a1.y) * w);
        ov.z = f2bf((a0.z + a1.z) * w);
        ov.w = f2bf((a0.w + a1.w) * w);
        *(ushort4*)(o + t * 4) = ov;
    } else if (t < 80) {                      // zero pad cols 300..319
        ushort4 z = {0, 0, 0, 0};
        *(ushort4*)(o + t * 4) = z;
    }
}

// ---------------- bf16 MFMA GEMM (m97-style 128x128x32), used for GEMM1 ----------------

template <int EPI>
__global__ __launch_bounds__(256) void k_mfma_gemm(const unsigned short* __restrict__ A, int lda,
                                                   const unsigned short* __restrict__ BT, int ldb,
                                                   const float* __restrict__ bias,
                                                   void* __restrict__ Cv,
                                                   int M, int N, int K) {
    __shared__ __align__(16) unsigned short As[128 * 32];
    __shared__ __align__(16) unsigned short Bs[128 * 32];
    int tid = threadIdx.x;
    int lane = tid & 63;
    int wid = tid >> 6;
    int wm = wid >> 1, wn = wid & 1;                 // 2x2 waves, 64x64 each
    int tcol, trow;
    xcd_tile(&tcol, &trow);
    int bm = trow * 128, bn = tcol * 128;

    f32x4 zero4 = {0.f, 0.f, 0.f, 0.f};
    f32x4 acc[4][4];
    #pragma unroll
    for (int i = 0; i < 4; ++i)
        #pragma unroll
        for (int j = 0; j < 4; ++j) acc[i][j] = zero4;

    int srow = tid >> 2;                // 0..63
    int scol = (tid & 3) * 8;           // k-elem offset (16B)
    int ar0 = bm + srow;      if (ar0 >= M) ar0 = M - 1;
    int ar1 = bm + srow + 64; if (ar1 >= M) ar1 = M - 1;
    const unsigned short* gA0 = A + (size_t)ar0 * lda + scol;
    const unsigned short* gA1 = A + (size_t)ar1 * lda + scol;
    const unsigned short* gB0 = BT + (size_t)(bn + srow) * ldb + scol;
    const unsigned short* gB1 = BT + (size_t)(bn + srow + 64) * ldb + scol;

    int kq = (lane >> 4) * 8;           // k-slice within tile: 0/8/16/24
    int rsel = lane & 15;

    for (int k0 = 0; k0 < K; k0 += 32) {
        gload16(gA0 + k0, &As[(size_t)tid * 8]);
        gload16(gA1 + k0, &As[(size_t)(tid + 256) * 8]);
        gload16(gB0 + k0, &Bs[(size_t)tid * 8]);
        gload16(gB1 + k0, &Bs[(size_t)(tid + 256) * 8]);
        __syncthreads();

        bf16x8 af[4], bfr[4];
        #pragma unroll
        for (int i = 0; i < 4; ++i) {
            af[i]  = *(const bf16x8*)&As[(wm * 64 + i * 16 + rsel) * 32 + kq];
            bfr[i] = *(const bf16x8*)&Bs[(wn * 64 + i * 16 + rsel) * 32 + kq];
        }
        #pragma unroll
        for (int i = 0; i < 4; ++i)
            #pragma unroll
            for (int j = 0; j < 4; ++j)
                acc[i][j] = __builtin_amdgcn_mfma_f32_16x16x32_bf16(af[i], bfr[j], acc[i][j], 0, 0, 0);
        __syncthreads();
    }

    // C/D layout (m89-verified): col = lane&15, row = (lane>>4)*4 + reg
    #pragma unroll
    for (int i = 0; i < 4; ++i) {
        int row_base = bm + wm * 64 + i * 16 + (lane >> 4) * 4;
        #pragma unroll
        for (int j = 0; j < 4; ++j) {
            int colg = bn + wn * 64 + j * 16 + (lane & 15);
            float bv = (EPI == 1) ? bias[colg] : 0.0f;
            #pragma unroll
            for (int r = 0; r < 4; ++r) {
                int row = row_base + r;
                if (row < M) {
                    float v = acc[i][j][r];
                    if (EPI == 1) {
                        v += bv; v = (v >= 0.f) ? v : 0.2f * v;
                        ((unsigned short*)Cv)[(size_t)row * N + colg] = f2bf(v);
                    } else {
                        ((unsigned char*)Cv)[(size_t)row * N + colg] = f2fp8(v * 32.0f);
                    }
                }
            }
        }
    }
}

// ---------------- 256x256 bf16 GEMM -> fp8 C: 4-buffer ring, stage 2 tiles ahead ----------------
// r17 NaN root cause: global_load_lds writes LDS at WAVE-UNIFORM BASE + lane*16 (m104/m108);
// r17's P = tid*32+i*16 had lane-stride 32 -> half of each wave segment never written.
// Fixed here: P = wid*2048 + i*1024 + lane*16 (lane-stride exactly 16B, same as r14-16).
// Ring schedule: during tile t stage tile t+2 into buf[(t+2)&3]; tile-end vmcnt(4) waits on
// loads issued TWO TILES back (~1500+ cyc) while 4 stay in flight. k-order unchanged.

__global__ __launch_bounds__(512) void k_gemm8p_fp8(const unsigned short* __restrict__ A, int lda,
                                                    const unsigned short* __restrict__ BT, int ldb,
                                                    unsigned char* __restrict__ C,
                                                    int M, int N, int K) {
    __shared__ __align__(16) unsigned short As_l[4][8192];   // ring: [buf][swizzled 256x32]
    __shared__ __align__(16) unsigned short Bs_l[4][8192];

    const int tid  = threadIdx.x;
    const int lane = tid & 63;
    const int wid  = tid >> 6;          // 0..7
    const int wm   = wid >> 2;          // 0..1
    const int wn   = wid & 3;           // 0..3
    int tcol, trow;
    xcd_tile(&tcol, &trow);
    const int bm = trow * 256, bn = tcol * 256;

    // staging coords: part i = this wave's i-th 1KB chunk; lane-stride MUST be 16B
    int rA[2], rB[2], cc[2], ldst[2];
    #pragma unroll
    for (int i = 0; i < 2; ++i) {
        int P = wid * 2048 + i * 1024 + lane * 16;          // phys byte in 16 KiB buffer
        int L = P ^ (((P >> 7) & 3) << 4);                  // logical byte (involution)
        int r = L >> 6;                                     // row 0..255
        cc[i] = (L & 63) >> 1;                              // col elem 0/8/16/24
        int ra = bm + r; if (ra >= M) ra = M - 1;
        rA[i] = ra;
        rB[i] = bn + r;                                     // N multiple of 256
        ldst[i] = P >> 1;                                   // ushort offset
    }

    // ds_read offsets (ushort) per fragment within a [256][32] buffer (T2 swizzle)
    const int rsel = lane & 15, kq8 = (lane >> 4) * 8;
    int aoff[8], boff[4];
    #pragma unroll
    for (int fi = 0; fi < 8; ++fi) {
        int row = wm * 128 + fi * 16 + rsel;
        aoff[fi] = row * 32 + (kq8 ^ (((row >> 1) & 3) << 3));
    }
    #pragma unroll
    for (int fj = 0; fj < 4; ++fj) {
        int row = wn * 64 + fj * 16 + rsel;
        boff[fj] = row * 32 + (kq8 ^ (((row >> 1) & 3) << 3));
    }

    f32x4 acc[8][4];
    #pragma unroll
    for (int fi = 0; fi < 8; ++fi)
        #pragma unroll
        for (int fj = 0; fj < 4; ++fj) { f32x4 z = {0.f,0.f,0.f,0.f}; acc[fi][fj] = z; }

    // stage part i (one A-load + one B-load) of tile with k-offset k0 into ring buf b
    #define STAGE_P(b, k0, i) do { \
        gload16(A  + (size_t)rA[i] * lda + (k0) + cc[i], &As_l[b][ldst[i]]); \
        gload16(BT + (size_t)rB[i] * ldb + (k0) + cc[i], &Bs_l[b][ldst[i]]); \
    } while (0)

    const int NT = K / 32;              // 64 tiles

    // prologue: stage tiles 0 and 1 (4 loads each); wait tile 0 (leave tile 1's 4 in flight)
    STAGE_P(0, 0, 0);  STAGE_P(0, 0, 1);
    STAGE_P(1, 32, 0); STAGE_P(1, 32, 1);
    asm volatile("s_waitcnt vmcnt(4)\n\ts_barrier" ::: "memory");

    for (int t = 0; t < NT; ++t) {
        const int bt = t & 3;
        const bool pf = (t + 2 < NT);
        const int kn = (t + 2) * 32;
        // ---- phase 0: stage part0 of tile t+2; A-frags 0-3 x B (16 MFMA) ----
        if (pf) STAGE_P((t + 2) & 3, kn, 0);
        bf16x8 bfv[4];
        #pragma unroll
        for (int fj = 0; fj < 4; ++fj) bfv[fj] = *(const bf16x8*)&Bs_l[bt][boff[fj]];
        {
            bf16x8 af[4];
            #pragma unroll
            for (int fi = 0; fi < 4; ++fi) af[fi] = *(const bf16x8*)&As_l[bt][aoff[fi]];
            __builtin_amdgcn_s_setprio(1);
            #pragma unroll
            for (int fi = 0; fi < 4; ++fi)
                #pragma unroll
                for (int fj = 0; fj < 4; ++fj)
                    acc[fi][fj] = __builtin_amdgcn_mfma_f32_16x16x32_bf16(af[fi], bfv[fj], acc[fi][fj], 0, 0, 0);
            __builtin_amdgcn_s_setprio(0);
        }
        // ---- phase 1: stage part1 of tile t+2; A-frags 4-7 x B (16 MFMA) ----
        if (pf) STAGE_P((t + 2) & 3, kn, 1);
        {
            bf16x8 af[4];
            #pragma unroll
            for (int fi = 0; fi < 4; ++fi) af[fi] = *(const bf16x8*)&As_l[bt][aoff[fi + 4]];
            __builtin_amdgcn_s_setprio(1);
            #pragma unroll
            for (int fi = 0; fi < 4; ++fi)
                #pragma unroll
                for (int fj = 0; fj < 4; ++fj)
                    acc[fi + 4][fj] = __builtin_amdgcn_mfma_f32_16x16x32_bf16(af[fi], bfv[fj], acc[fi + 4][fj], 0, 0, 0);
            __builtin_amdgcn_s_setprio(0);
        }
        // ---- tile boundary: next tile's data (staged 2 tiles ago) must be landed ----
        if (pf)                asm volatile("s_waitcnt vmcnt(4)\n\ts_barrier" ::: "memory");
        else if (t + 2 == NT)  asm volatile("s_waitcnt vmcnt(0)\n\ts_barrier" ::: "memory");
        // t == NT-1: register-only epilogue follows, no wait
    }
    #undef STAGE_P

    // epilogue: C/D layout col=lane&15, row=(lane>>4)*4+reg
    #pragma unroll
    for (int fi = 0; fi < 8; ++fi) {
        int row_base = bm + wm * 128 + fi * 16 + (lane >> 4) * 4;
        #pragma unroll
        for (int fj = 0; fj < 4; ++fj) {
            int colg = bn + wn * 64 + fj * 16 + (lane & 15);
            #pragma unroll
            for (int r = 0; r < 4; ++r) {
                int row = row_base + r;
                if (row < M) C[(size_t)row * N + colg] = f2fp8(acc[fi][fj][r] * 32.0f);
            }
        }
    }
}

// ---------------- SpMM2 (fp8 H2, x32-scaled) + bias + row L2 normalize ----------------

__global__ __launch_bounds__(256) void k_spmm2_norm(const int* __restrict__ ptr, const int* __restrict__ col,
                                                    const unsigned char* __restrict__ H2,
                                                    const float* __restrict__ b2,
                                                    float* __restrict__ out) {
    const int C = 2048;
    int r = blockIdx.x, t = threadIdx.x;
    int s = ptr[r], e = ptr[r + 1];
    float ac0[8] = {}, ac1[8] = {}, ac2[8] = {}, ac3[8] = {};
    const uint2* base = (const uint2*)(H2 + t * 8);   // row stride = 2048 B = 256 uint2
    int p = s;
    for (; p + 3 < e; p += 4) {
        uint2 w0 = base[(size_t)col[p]     * 256];
        uint2 w1 = base[(size_t)col[p + 1] * 256];
        uint2 w2 = base[(size_t)col[p + 2] * 256];
        uint2 w3 = base[(size_t)col[p + 3] * 256];
        ACC8(ac0, w0); ACC8(ac1, w1); ACC8(ac2, w2); ACC8(ac3, w3);
    }
    for (; p < e; ++p) {
        uint2 w = base[(size_t)col[p] * 256];
        ACC8(ac0, w);
    }
    float w = 1.0f / (32.0f * fmaxf((float)(e - s), 1.0f));   // undo x32 fp8 scale + degree avg
    float ss = 0.f;
    float vv[8];
    #pragma unroll
    for (int j = 0; j < 8; ++j) {
        float v = (ac0[j] + ac1[j] + ac2[j] + ac3[j]) * w + b2[t * 8 + j];
        vv[j] = v;
        ss += v * v;
    }
    __shared__ float red[4];
    __shared__ float scale_s;
    #pragma unroll
    for (int off = 32; off > 0; off >>= 1) ss += __shfl_down(ss, off, 64);
    int lane = t & 63, wid = t >> 6;
    if (lane == 0) red[wid] = ss;
    __syncthreads();
    if (t == 0) {
        float tot = red[0] + red[1] + red[2] + red[3];
        scale_s = 1.0f / fmaxf(sqrtf(tot), 1e-12f);
    }
    __syncthreads();
    float sc = scale_s;
    float* o = out + (size_t)r * C + t * 8;
    float4 o0 = {vv[0] * sc, vv[1] * sc, vv[2] * sc, vv[3] * sc};
    float4 o1 = {vv[4] * sc, vv[5] * sc, vv[6] * sc, vv[7] * sc};
    *(float4*)o = o0;
    *(float4*)(o + 4) = o1;
}

// ---------------- launch ----------------

extern "C" void kernel_launch(void* const* d_in, const int* in_sizes, int n_in,
                              void* d_out, int out_size, void* d_ws, size_t ws_size,
                              hipStream_t stream) {
    const float* x  = (const float*)d_in[0];
    const float* W1 = (const float*)d_in[1];
    const float* b1 = (const float*)d_in[2];
    const float* W2 = (const float*)d_in[3];
    const float* b2 = (const float*)d_in[4];
    const int* erow = (const int*)d_in[5];
    const int* ecol = (const int*)d_in[6];

    const int chid = in_sizes[2];              // 2048
    const int cout = in_sizes[4];              // 2048
    const int cin  = in_sizes[1] / chid;       // 300
    const int n    = in_sizes[0] / cin;        // 50000
    const int e    = in_sizes[5];              // 1600000
    const int cinp = (cin + 31) & ~31;         // 320 (K-pad for MFMA)

    char* ws = (char*)d_ws;
    size_t off = 0;
    auto alloc = [&](size_t bytes) -> void* {
        void* p = ws + off;
        off += (bytes + 255) & ~(size_t)255;
        return p;
    };
    int*            deg     = (int*)alloc((size_t)n * 4);
    int*            ptr     = (int*)alloc((size_t)(n + 1) * 4);
    int*            cursor  = (int*)alloc((size_t)n * 4);
    int*            csr_col = (int*)alloc((size_t)e * 4);
    unsigned short* ax      = (unsigned short*)alloc((size_t)n * cinp * 2);
    unsigned short* W1T     = (unsigned short*)alloc((size_t)chid * cinp * 2);
    unsigned short* W2T     = (unsigned short*)alloc((size_t)cout * chid * 2);
    unsigned char*  H2f8    = (unsigned char*)alloc((size_t)n * cout);
    unsigned short* H1      = (unsigned short*)d_out;   // bf16 H1 stashed in d_out; fully overwritten at the end

    k_zero_i32<<<(n + 255) / 256, 256, 0, stream>>>(deg, n);
    k_count_deg<<<2048, 256, 0, stream>>>(erow, deg, e);
    k_scan<<<1, 1024, 0, stream>>>(deg, ptr, cursor, n);
    k_scatter<<<2048, 256, 0, stream>>>(erow, ecol, cursor, csr_col, e);

    dim3 gw1(cinp / 32, chid / 32);
    k_cvt_wT<<<gw1, 256, 0, stream>>>(W1, W1T, cin, chid, cinp);
    dim3 gw2(chid / 32, cout / 32);
    k_cvt_wT<<<gw2, 256, 0, stream>>>(W2, W2T, chid, cout, chid);

    k_spmm1<<<n, 128, 0, stream>>>(ptr, csr_col, x, ax);

    dim3 g1(chid / 128, (n + 127) / 128);   // 16 x 391 blocks; XCD swizzle active (6256 % 8 == 0)
    // H1 = bf16(LeakyReLU((A@X)bf16 @ W1 + b1))
    k_mfma_gemm<1><<<g1, 256, 0, stream>>>(ax, cinp, W1T, cinp, b1, (void*)H1, n, chid, cinp);

    dim3 g2(cout / 256, (n + 255) / 256);   // 8 x 196 blocks; XCD swizzle active
    // H2 = fp8(32 * (H1 @ W2))  -- 4-buf ring pipelined kernel (lane-stride-16 staging fix)
    k_gemm8p_fp8<<<g2, 512, 0, stream>>>(H1, chid, W2T, chid, H2f8, n, cout, chid);

    // out = normalize(A @ H2 + b2)
    k_spmm2_norm<<<n, 256, 0, stream>>>(ptr, csr_col, H2f8, b2, (float*)d_out);
}

// Round 20
// 1821.054 us; speedup vs baseline: 1.0224x; 1.0224x over previous
//
#include <hip/hip_runtime.h>
#include <math.h>

typedef unsigned short ushort_t;
using bf16x8  = __attribute__((ext_vector_type(8))) short;
using f32x4   = __attribute__((ext_vector_type(4))) float;
using ushort8 = __attribute__((ext_vector_type(8))) unsigned short;

__device__ __forceinline__ unsigned short f2bf(float f) {
    union { float f; unsigned int u; } v; v.f = f;
    unsigned int r = v.u + 0x7FFFu + ((v.u >> 16) & 1u);   // RNE
    return (unsigned short)(r >> 16);
}
__device__ __forceinline__ float bf2f(unsigned short u) {
    union { unsigned int u; float f; } v; v.u = ((unsigned int)u) << 16;
    return v.f;
}

// ---- fp8 e4m3 (OCP) helpers: HW cvt when available, manual fallback ----
#if defined(__has_builtin)
#if __has_builtin(__builtin_amdgcn_cvt_f32_fp8) && __has_builtin(__builtin_amdgcn_cvt_pk_fp8_f32)
#define FP8_HW 1
#endif
#endif

__device__ __forceinline__ unsigned char f2fp8(float v) {
#ifdef FP8_HW
    unsigned int p = __builtin_amdgcn_cvt_pk_fp8_f32(v, v, 0, false);
    return (unsigned char)(p & 0xFFu);
#else
    union { float f; unsigned u; } b; b.f = v;
    unsigned s = (b.u >> 24) & 0x80u;
    float a = fabsf(v);
    if (a >= 448.f) return (unsigned char)(s | 0x7E);
    if (a < 0.015625f) {                      // subnormal: m = round(a * 512)
        int m = (int)rintf(a * 512.0f);
        if (m >= 8) return (unsigned char)(s | 0x08);
        return (unsigned char)(s | (unsigned)m);
    }
    unsigned u = b.u & 0x7FFFFFFFu;
    u += 0x7FFFFu + ((u >> 20) & 1u);        // RNE at mantissa bit 20
    int e8 = (int)((u >> 23) & 0xFF) - 120;
    unsigned M = (u >> 20) & 7u;
    if (e8 > 15 || (e8 == 15 && M == 7u)) return (unsigned char)(s | 0x7E);
    return (unsigned char)(s | ((unsigned)e8 << 3) | M);
#endif
}

#ifdef FP8_HW
#define ACC8(ac, w) do { \
    ac[0] += __builtin_amdgcn_cvt_f32_fp8((int)(w).x, 0); \
    ac[1] += __builtin_amdgcn_cvt_f32_fp8((int)(w).x, 1); \
    ac[2] += __builtin_amdgcn_cvt_f32_fp8((int)(w).x, 2); \
    ac[3] += __builtin_amdgcn_cvt_f32_fp8((int)(w).x, 3); \
    ac[4] += __builtin_amdgcn_cvt_f32_fp8((int)(w).y, 0); \
    ac[5] += __builtin_amdgcn_cvt_f32_fp8((int)(w).y, 1); \
    ac[6] += __builtin_amdgcn_cvt_f32_fp8((int)(w).y, 2); \
    ac[7] += __builtin_amdgcn_cvt_f32_fp8((int)(w).y, 3); \
} while (0)
#else
__device__ __forceinline__ float fp82f(unsigned u) {
    unsigned s = u >> 7, e = (u >> 3) & 15u, m = u & 7u;
    union { unsigned u; float f; } nb;
    nb.u = (s << 31) | ((e + 120u) << 23) | (m << 20);
    float sub = (float)(int)m * 0.001953125f;
    sub = s ? -sub : sub;
    return e ? nb.f : sub;
}
#define ACC8(ac, w) do { \
    ac[0] += fp82f(((w).x      ) & 0xFFu); \
    ac[1] += fp82f(((w).x >>  8) & 0xFFu); \
    ac[2] += fp82f(((w).x >> 16) & 0xFFu); \
    ac[3] += fp82f(((w).x >> 24)        ); \
    ac[4] += fp82f(((w).y      ) & 0xFFu); \
    ac[5] += fp82f(((w).y >>  8) & 0xFFu); \
    ac[6] += fp82f(((w).y >> 16) & 0xFFu); \
    ac[7] += fp82f(((w).y >> 24)        ); \
} while (0)
#endif

typedef const __attribute__((address_space(1))) void* gas_ptr;
typedef __attribute__((address_space(3))) void* las_ptr;
__device__ __forceinline__ void gload16(const void* g, void* l) {
    __builtin_amdgcn_global_load_lds((gas_ptr)g, (las_ptr)l, 16, 0, 0);
}

// ---------------- CSR build ----------------

__global__ void k_zero_i32(int* __restrict__ p, int n) {
    int i = blockIdx.x * blockDim.x + threadIdx.x;
    if (i < n) p[i] = 0;
}

__global__ void k_count_deg(const int* __restrict__ erow, int* __restrict__ deg, int e) {
    for (int i = blockIdx.x * blockDim.x + threadIdx.x; i < e; i += gridDim.x * blockDim.x)
        atomicAdd(&deg[erow[i]], 1);
}

__global__ __launch_bounds__(1024) void k_scan(const int* __restrict__ deg, int* __restrict__ ptr,
                                               int* __restrict__ cursor, int n) {
    __shared__ int buf[1024];
    __shared__ int carry_s;
    int t = threadIdx.x;
    if (t == 0) { carry_s = 0; ptr[0] = 0; }
    __syncthreads();
    for (int base = 0; base < n; base += 1024) {
        int i = base + t;
        int v = (i < n) ? deg[i] : 0;
        buf[t] = v;
        __syncthreads();
        #pragma unroll
        for (int off = 1; off < 1024; off <<= 1) {
            int xv = (t >= off) ? buf[t - off] : 0;
            __syncthreads();
            buf[t] += xv;
            __syncthreads();
        }
        int carry = carry_s;
        int incl = buf[t] + carry;
        if (i < n) { ptr[i + 1] = incl; cursor[i] = incl - v; }
        int bsum = buf[1023];
        __syncthreads();
        if (t == 0) carry_s = carry + bsum;
        __syncthreads();
    }
}

__global__ void k_scatter(const int* __restrict__ erow, const int* __restrict__ ecol,
                          int* __restrict__ cursor, int* __restrict__ csr_col, int e) {
    for (int i = blockIdx.x * blockDim.x + threadIdx.x; i < e; i += gridDim.x * blockDim.x) {
        int pos = atomicAdd(&cursor[erow[i]], 1);
        csr_col[pos] = ecol[i];
    }
}

// ---------------- transpose + fp32->bf16: WT[n][kp] = bf16(W[kp][n]), kp>=K -> 0 ----------------

__global__ __launch_bounds__(256) void k_cvt_wT(const float* __restrict__ W, unsigned short* __restrict__ WT,
                                                int K, int N, int Kpad) {
    __shared__ float tile[32][33];
    int kp0 = blockIdx.x * 32, n0 = blockIdx.y * 32;
    int tx = threadIdx.x & 31, ty = threadIdx.x >> 5;   // 32 x 8
    #pragma unroll
    for (int ii = 0; ii < 4; ++ii) {
        int k = kp0 + ty + ii * 8;
        tile[ty + ii * 8][tx] = (k < K) ? W[(size_t)k * N + n0 + tx] : 0.0f;
    }
    __syncthreads();
    #pragma unroll
    for (int ii = 0; ii < 4; ++ii) {
        int n = n0 + ty + ii * 8;
        WT[(size_t)n * Kpad + kp0 + tx] = f2bf(tile[tx][ty + ii * 8]);
    }
}

// ---------------- SpMM1 (fp32 x): ax[i][:] = bf16( (1/deg_i) * sum x[col][:] ), out 320-wide ----------------
// X stays fp32: round-12 showed bf16-X overruns the absmax budget (2.44e-3 > 2.13e-3).

__global__ __launch_bounds__(128) void k_spmm1(const int* __restrict__ ptr, const int* __restrict__ col,
                                               const float* __restrict__ x, unsigned short* __restrict__ ax) {
    int r = blockIdx.x;
    int t = threadIdx.x;
    int s = ptr[r], e = ptr[r + 1];
    bool act = t < 75;
    const float4* xb = (const float4*)x;
    float4 a0 = {0.f, 0.f, 0.f, 0.f}, a1 = {0.f, 0.f, 0.f, 0.f};
    int p = s;
    for (; p + 1 < e; p += 2) {
        int c0 = col[p], c1 = col[p + 1];
        if (act) {
            float4 v0 = xb[(size_t)c0 * 75 + t];
            float4 v1 = xb[(size_t)c1 * 75 + t];
            a0.x += v0.x; a0.y += v0.y; a0.z += v0.z; a0.w += v0.w;
            a1.x += v1.x; a1.y += v1.y; a1.z += v1.z; a1.w += v1.w;
        }
    }
    if (p < e && act) {
        float4 v = xb[(size_t)col[p] * 75 + t];
        a0.x += v.x; a0.y += v.y; a0.z += v.z; a0.w += v.w;
    }
    float w = 1.0f / fmaxf((float)(e - s), 1.0f);
    unsigned short* o = ax + (size_t)r * 320;
    if (act) {
        ushort4 ov;
        ov.x = f2bf((a0.x + a1.x) * w);
        ov.y = f2bf((a0.y + a1.y) * w);
        ov.z = f2bf((a0.z + a1.z) * w);
        ov.w = f2bf((a0.w + a1.w) * w);
        *(ushort4*)(o + t * 4) = ov;
    } else if (t < 80) {                      // zero pad cols 300..319
        ushort4 z = {0, 0, 0, 0};
        *(ushort4*)(o + t * 4) = z;
    }
}

// ---------------- bf16 MFMA GEMM: C[M][N] = A[M][lda] @ BT[N][ldb]^T  (m97-style 128x128x32) ----------------
// Grid: (N/128, M/128) -- blockIdx.x (FAST) = column tile, so consecutive blocks
// share one A-tile (L2-resident) and sweep B (L3-resident); A read ~once from HBM.
// EPI 1: bf16(leaky(acc+bias)) -> ushort C.   EPI 2: fp8(32*acc) -> uchar C.

template <int EPI>
__global__ __launch_bounds__(256) void k_mfma_gemm(const unsigned short* __restrict__ A, int lda,
                                                   const unsigned short* __restrict__ BT, int ldb,
                                                   const float* __restrict__ bias,
                                                   void* __restrict__ Cv,
                                                   int M, int N, int K) {
    __shared__ __align__(16) unsigned short As[128 * 32];
    __shared__ __align__(16) unsigned short Bs[128 * 32];
    int tid = threadIdx.x;
    int lane = tid & 63;
    int wid = tid >> 6;
    int wm = wid >> 1, wn = wid & 1;                 // 2x2 waves, 64x64 each
    int bm = blockIdx.y * 128, bn = blockIdx.x * 128;   // x = column tile (fast)

    f32x4 zero4 = {0.f, 0.f, 0.f, 0.f};
    f32x4 acc[4][4];
    #pragma unroll
    for (int i = 0; i < 4; ++i)
        #pragma unroll
        for (int j = 0; j < 4; ++j) acc[i][j] = zero4;

    int srow = tid >> 2;                // 0..63
    int scol = (tid & 3) * 8;           // k-elem offset (16B)
    int ar0 = bm + srow;      if (ar0 >= M) ar0 = M - 1;
    int ar1 = bm + srow + 64; if (ar1 >= M) ar1 = M - 1;
    const unsigned short* gA0 = A + (size_t)ar0 * lda + scol;
    const unsigned short* gA1 = A + (size_t)ar1 * lda + scol;
    const unsigned short* gB0 = BT + (size_t)(bn + srow) * ldb + scol;
    const unsigned short* gB1 = BT + (size_t)(bn + srow + 64) * ldb + scol;

    int kq = (lane >> 4) * 8;           // k-slice within tile: 0/8/16/24
    int rsel = lane & 15;

    for (int k0 = 0; k0 < K; k0 += 32) {
        gload16(gA0 + k0, &As[(size_t)tid * 8]);
        gload16(gA1 + k0, &As[(size_t)(tid + 256) * 8]);
        gload16(gB0 + k0, &Bs[(size_t)tid * 8]);
        gload16(gB1 + k0, &Bs[(size_t)(tid + 256) * 8]);
        __syncthreads();

        bf16x8 af[4], bfr[4];
        #pragma unroll
        for (int i = 0; i < 4; ++i) {
            af[i]  = *(const bf16x8*)&As[(wm * 64 + i * 16 + rsel) * 32 + kq];
            bfr[i] = *(const bf16x8*)&Bs[(wn * 64 + i * 16 + rsel) * 32 + kq];
        }
        #pragma unroll
        for (int i = 0; i < 4; ++i)
            #pragma unroll
            for (int j = 0; j < 4; ++j)
                acc[i][j] = __builtin_amdgcn_mfma_f32_16x16x32_bf16(af[i], bfr[j], acc[i][j], 0, 0, 0);
        __syncthreads();
    }

    // C/D layout (m89-verified): col = lane&15, row = (lane>>4)*4 + reg
    #pragma unroll
    for (int i = 0; i < 4; ++i) {
        int row_base = bm + wm * 64 + i * 16 + (lane >> 4) * 4;
        #pragma unroll
        for (int j = 0; j < 4; ++j) {
            int colg = bn + wn * 64 + j * 16 + (lane & 15);
            float bv = (EPI == 1) ? bias[colg] : 0.0f;
            #pragma unroll
            for (int r = 0; r < 4; ++r) {
                int row = row_base + r;
                if (row < M) {
                    float v = acc[i][j][r];
                    if (EPI == 1) {
                        v += bv; v = (v >= 0.f) ? v : 0.2f * v;
                        ((unsigned short*)Cv)[(size_t)row * N + colg] = f2bf(v);
                    } else {
                        ((unsigned char*)Cv)[(size_t)row * N + colg] = f2fp8(v * 32.0f);
                    }
                }
            }
        }
    }
}

// ---------------- SpMM2 (fp8 H2, x32-scaled) + bias + row L2 normalize ----------------

__global__ __launch_bounds__(256) void k_spmm2_norm(const int* __restrict__ ptr, const int* __restrict__ col,
                                                    const unsigned char* __restrict__ H2,
                                                    const float* __restrict__ b2,
                                                    float* __restrict__ out) {
    const int C = 2048;
    int r = blockIdx.x, t = threadIdx.x;
    int s = ptr[r], e = ptr[r + 1];
    float ac0[8] = {}, ac1[8] = {}, ac2[8] = {}, ac3[8] = {};
    const uint2* base = (const uint2*)(H2 + t * 8);   // row stride = 2048 B = 256 uint2
    int p = s;
    for (; p + 3 < e; p += 4) {
        uint2 w0 = base[(size_t)col[p]     * 256];
        uint2 w1 = base[(size_t)col[p + 1] * 256];
        uint2 w2 = base[(size_t)col[p + 2] * 256];
        uint2 w3 = base[(size_t)col[p + 3] * 256];
        ACC8(ac0, w0); ACC8(ac1, w1); ACC8(ac2, w2); ACC8(ac3, w3);
    }
    for (; p < e; ++p) {
        uint2 w = base[(size_t)col[p] * 256];
        ACC8(ac0, w);
    }
    float w = 1.0f / (32.0f * fmaxf((float)(e - s), 1.0f));   // undo x32 fp8 scale + degree avg
    float ss = 0.f;
    float vv[8];
    #pragma unroll
    for (int j = 0; j < 8; ++j) {
        float v = (ac0[j] + ac1[j] + ac2[j] + ac3[j]) * w + b2[t * 8 + j];
        vv[j] = v;
        ss += v * v;
    }
    __shared__ float red[4];
    __shared__ float scale_s;
    #pragma unroll
    for (int off = 32; off > 0; off >>= 1) ss += __shfl_down(ss, off, 64);
    int lane = t & 63, wid = t >> 6;
    if (lane == 0) red[wid] = ss;
    __syncthreads();
    if (t == 0) {
        float tot = red[0] + red[1] + red[2] + red[3];
        scale_s = 1.0f / fmaxf(sqrtf(tot), 1e-12f);
    }
    __syncthreads();
    float sc = scale_s;
    float* o = out + (size_t)r * C + t * 8;
    float4 o0 = {vv[0] * sc, vv[1] * sc, vv[2] * sc, vv[3] * sc};
    float4 o1 = {vv[4] * sc, vv[5] * sc, vv[6] * sc, vv[7] * sc};
    *(float4*)o = o0;
    *(float4*)(o + 4) = o1;
}

// ---------------- launch ----------------

extern "C" void kernel_launch(void* const* d_in, const int* in_sizes, int n_in,
                              void* d_out, int out_size, void* d_ws, size_t ws_size,
                              hipStream_t stream) {
    const float* x  = (const float*)d_in[0];
    const float* W1 = (const float*)d_in[1];
    const float* b1 = (const float*)d_in[2];
    const float* W2 = (const float*)d_in[3];
    const float* b2 = (const float*)d_in[4];
    const int* erow = (const int*)d_in[5];
    const int* ecol = (const int*)d_in[6];

    const int chid = in_sizes[2];              // 2048
    const int cout = in_sizes[4];              // 2048
    const int cin  = in_sizes[1] / chid;       // 300
    const int n    = in_sizes[0] / cin;        // 50000
    const int e    = in_sizes[5];              // 1600000
    const int cinp = (cin + 31) & ~31;         // 320 (K-pad for MFMA)

    char* ws = (char*)d_ws;
    size_t off = 0;
    auto alloc = [&](size_t bytes) -> void* {
        void* p = ws + off;
        off += (bytes + 255) & ~(size_t)255;
        return p;
    };
    int*            deg     = (int*)alloc((size_t)n * 4);
    int*            ptr     = (int*)alloc((size_t)(n + 1) * 4);
    int*            cursor  = (int*)alloc((size_t)n * 4);
    int*            csr_col = (int*)alloc((size_t)e * 4);
    unsigned short* ax      = (unsigned short*)alloc((size_t)n * cinp * 2);
    unsigned short* W1T     = (unsigned short*)alloc((size_t)chid * cinp * 2);
    unsigned short* W2T     = (unsigned short*)alloc((size_t)cout * chid * 2);
    unsigned char*  H2f8    = (unsigned char*)alloc((size_t)n * cout);
    unsigned short* H1      = (unsigned short*)d_out;   // bf16 H1 stashed in d_out; fully overwritten at the end

    k_zero_i32<<<(n + 255) / 256, 256, 0, stream>>>(deg, n);
    k_count_deg<<<2048, 256, 0, stream>>>(erow, deg, e);
    k_scan<<<1, 1024, 0, stream>>>(deg, ptr, cursor, n);
    k_scatter<<<2048, 256, 0, stream>>>(erow, ecol, cursor, csr_col, e);

    dim3 gw1(cinp / 32, chid / 32);
    k_cvt_wT<<<gw1, 256, 0, stream>>>(W1, W1T, cin, chid, cinp);
    dim3 gw2(chid / 32, cout / 32);
    k_cvt_wT<<<gw2, 256, 0, stream>>>(W2, W2T, chid, cout, chid);

    k_spmm1<<<n, 128, 0, stream>>>(ptr, csr_col, x, ax);

    dim3 g1(chid / 128, (n + 127) / 128);   // x = column tile (fast) for A-reuse
    // H1 = bf16(LeakyReLU((A@X)bf16 @ W1 + b1))
    k_mfma_gemm<1><<<g1, 256, 0, stream>>>(ax, cinp, W1T, cinp, b1, (void*)H1, n, chid, cinp);

    dim3 g2(cout / 128, (n + 127) / 128);   // x = column tile (fast)
    // H2 = fp8(32 * (H1 @ W2))
    k_mfma_gemm<2><<<g2, 256, 0, stream>>>(H1, chid, W2T, chid, (const float*)nullptr, (void*)H2f8, n, cout, chid);

    // out = normalize(A @ H2 + b2)
    k_spmm2_norm<<<n, 256, 0, stream>>>(ptr, csr_col, H2f8, b2, (float*)d_out);
}

// Round 23
// 1698.657 us; speedup vs baseline: 1.0960x; 1.0721x over previous
//
#include <hip/hip_runtime.h>
#include <math.h>

typedef unsigned short ushort_t;
using bf16x8  = __attribute__((ext_vector_type(8))) short;
using f32x4   = __attribute__((ext_vector_type(4))) float;
using ushort8 = __attribute__((ext_vector_type(8))) unsigned short;

__device__ __forceinline__ unsigned short f2bf(float f) {
    union { float f; unsigned int u; } v; v.f = f;
    unsigned int r = v.u + 0x7FFFu + ((v.u >> 16) & 1u);   // RNE
    return (unsigned short)(r >> 16);
}
__device__ __forceinline__ float bf2f(unsigned short u) {
    union { unsigned int u; float f; } v; v.u = ((unsigned int)u) << 16;
    return v.f;
}

// ---- fp8 e4m3 (OCP) helpers: HW cvt when available, manual fallback ----
#if defined(__has_builtin)
#if __has_builtin(__builtin_amdgcn_cvt_f32_fp8) && __has_builtin(__builtin_amdgcn_cvt_pk_fp8_f32)
#define FP8_HW 1
#endif
#endif

__device__ __forceinline__ unsigned char f2fp8(float v) {
#ifdef FP8_HW
    unsigned int p = __builtin_amdgcn_cvt_pk_fp8_f32(v, v, 0, false);
    return (unsigned char)(p & 0xFFu);
#else
    union { float f; unsigned u; } b; b.f = v;
    unsigned s = (b.u >> 24) & 0x80u;
    float a = fabsf(v);
    if (a >= 448.f) return (unsigned char)(s | 0x7E);
    if (a < 0.015625f) {                      // subnormal: m = round(a * 512)
        int m = (int)rintf(a * 512.0f);
        if (m >= 8) return (unsigned char)(s | 0x08);
        return (unsigned char)(s | (unsigned)m);
    }
    unsigned u = b.u & 0x7FFFFFFFu;
    u += 0x7FFFFu + ((u >> 20) & 1u);        // RNE at mantissa bit 20
    int e8 = (int)((u >> 23) & 0xFF) - 120;
    unsigned M = (u >> 20) & 7u;
    if (e8 > 15 || (e8 == 15 && M == 7u)) return (unsigned char)(s | 0x7E);
    return (unsigned char)(s | ((unsigned)e8 << 3) | M);
#endif
}

#ifdef FP8_HW
#define ACC8(ac, w) do { \
    ac[0] += __builtin_amdgcn_cvt_f32_fp8((int)(w).x, 0); \
    ac[1] += __builtin_amdgcn_cvt_f32_fp8((int)(w).x, 1); \
    ac[2] += __builtin_amdgcn_cvt_f32_fp8((int)(w).x, 2); \
    ac[3] += __builtin_amdgcn_cvt_f32_fp8((int)(w).x, 3); \
    ac[4] += __builtin_amdgcn_cvt_f32_fp8((int)(w).y, 0); \
    ac[5] += __builtin_amdgcn_cvt_f32_fp8((int)(w).y, 1); \
    ac[6] += __builtin_amdgcn_cvt_f32_fp8((int)(w).y, 2); \
    ac[7] += __builtin_amdgcn_cvt_f32_fp8((int)(w).y, 3); \
} while (0)
#else
__device__ __forceinline__ float fp82f(unsigned u) {
    unsigned s = u >> 7, e = (u >> 3) & 15u, m = u & 7u;
    union { unsigned u; float f; } nb;
    nb.u = (s << 31) | ((e + 120u) << 23) | (m << 20);
    float sub = (float)(int)m * 0.001953125f;
    sub = s ? -sub : sub;
    return e ? nb.f : sub;
}
#define ACC8(ac, w) do { \
    ac[0] += fp82f(((w).x      ) & 0xFFu); \
    ac[1] += fp82f(((w).x >>  8) & 0xFFu); \
    ac[2] += fp82f(((w).x >> 16) & 0xFFu); \
    ac[3] += fp82f(((w).x >> 24)        ); \
    ac[4] += fp82f(((w).y      ) & 0xFFu); \
    ac[5] += fp82f(((w).y >>  8) & 0xFFu); \
    ac[6] += fp82f(((w).y >> 16) & 0xFFu); \
    ac[7] += fp82f(((w).y >> 24)        ); \
} while (0)
#endif

typedef const __attribute__((address_space(1))) void* gas_ptr;
typedef __attribute__((address_space(3))) void* las_ptr;
__device__ __forceinline__ void gload16(const void* g, void* l) {
    __builtin_amdgcn_global_load_lds((gas_ptr)g, (las_ptr)l, 16, 0, 0);
}

// ---------------- CSR build ----------------

__global__ void k_zero_i32(int* __restrict__ p, int n) {
    int i = blockIdx.x * blockDim.x + threadIdx.x;
    if (i < n) p[i] = 0;
}

__global__ void k_count_deg(const int* __restrict__ erow, int* __restrict__ deg, int e) {
    for (int i = blockIdx.x * blockDim.x + threadIdx.x; i < e; i += gridDim.x * blockDim.x)
        atomicAdd(&deg[erow[i]], 1);
}

// 3-phase parallel prefix scan (replaces the serial single-block scan):
// phase 1: per-block inclusive scan of deg -> incl, block sums -> bsum
__global__ __launch_bounds__(1024) void k_scan1(const int* __restrict__ deg, int* __restrict__ incl,
                                                int* __restrict__ bsum, int n) {
    __shared__ int buf[1024];
    int t = threadIdx.x;
    int i = blockIdx.x * 1024 + t;
    buf[t] = (i < n) ? deg[i] : 0;
    __syncthreads();
    #pragma unroll
    for (int off = 1; off < 1024; off <<= 1) {
        int xv = (t >= off) ? buf[t - off] : 0;
        __syncthreads();
        buf[t] += xv;
        __syncthreads();
    }
    if (i < n) incl[i] = buf[t];
    if (t == 0) bsum[blockIdx.x] = buf[1023];
}

// phase 2: exclusive scan of the (tiny) block sums
__global__ void k_scan2(const int* __restrict__ bsum, int* __restrict__ boff, int nb) {
    if (threadIdx.x == 0 && blockIdx.x == 0) {
        int acc = 0;
        for (int i = 0; i < nb; ++i) { boff[i] = acc; acc += bsum[i]; }
    }
}

// phase 3: combine -> ptr (inclusive at i+1) and cursor (exclusive start per row)
__global__ __launch_bounds__(1024) void k_scan3(const int* __restrict__ deg, const int* __restrict__ incl,
                                                const int* __restrict__ boff, int* __restrict__ ptr,
                                                int* __restrict__ cursor, int n) {
    int i = blockIdx.x * 1024 + threadIdx.x;
    if (i < n) {
        int v = incl[i] + boff[blockIdx.x];
        ptr[i + 1] = v;
        cursor[i] = v - deg[i];
        if (i == 0) ptr[0] = 0;
    }
}

__global__ void k_scatter(const int* __restrict__ erow, const int* __restrict__ ecol,
                          int* __restrict__ cursor, int* __restrict__ csr_col, int e) {
    for (int i = blockIdx.x * blockDim.x + threadIdx.x; i < e; i += gridDim.x * blockDim.x) {
        int pos = atomicAdd(&cursor[erow[i]], 1);
        csr_col[pos] = ecol[i];
    }
}

// ---------------- transpose + fp32->bf16: WT[n][kp] = bf16(W[kp][n]), kp>=K -> 0 ----------------

__global__ __launch_bounds__(256) void k_cvt_wT(const float* __restrict__ W, unsigned short* __restrict__ WT,
                                                int K, int N, int Kpad) {
    __shared__ float tile[32][33];
    int kp0 = blockIdx.x * 32, n0 = blockIdx.y * 32;
    int tx = threadIdx.x & 31, ty = threadIdx.x >> 5;   // 32 x 8
    #pragma unroll
    for (int ii = 0; ii < 4; ++ii) {
        int k = kp0 + ty + ii * 8;
        tile[ty + ii * 8][tx] = (k < K) ? W[(size_t)k * N + n0 + tx] : 0.0f;
    }
    __syncthreads();
    #pragma unroll
    for (int ii = 0; ii < 4; ++ii) {
        int n = n0 + ty + ii * 8;
        WT[(size_t)n * Kpad + kp0 + tx] = f2bf(tile[tx][ty + ii * 8]);
    }
}

// ---------------- SpMM1 (fp32 x): ax[i][:] = bf16( (1/deg_i) * sum x[col][:] ), out 320-wide ----------------
// X stays fp32: round-12 showed bf16-X overruns the absmax budget (2.44e-3 > 2.13e-3).

__global__ __launch_bounds__(128) void k_spmm1(const int* __restrict__ ptr, const int* __restrict__ col,
                                               const float* __restrict__ x, unsigned short* __restrict__ ax) {
    int r = blockIdx.x;
    int t = threadIdx.x;
    int s = ptr[r], e = ptr[r + 1];
    bool act = t < 75;
    const float4* xb = (const float4*)x;
    float4 a0 = {0.f, 0.f, 0.f, 0.f}, a1 = {0.f, 0.f, 0.f, 0.f};
    int p = s;
    for (; p + 1 < e; p += 2) {
        int c0 = col[p], c1 = col[p + 1];
        if (act) {
            float4 v0 = xb[(size_t)c0 * 75 + t];
            float4 v1 = xb[(size_t)c1 * 75 + t];
            a0.x += v0.x; a0.y += v0.y; a0.z += v0.z; a0.w += v0.w;
            a1.x += v1.x; a1.y += v1.y; a1.z += v1.z; a1.w += v1.w;
        }
    }
    if (p < e && act) {
        float4 v = xb[(size_t)col[p] * 75 + t];
        a0.x += v.x; a0.y += v.y; a0.z += v.z; a0.w += v.w;
    }
    float w = 1.0f / fmaxf((float)(e - s), 1.0f);
    unsigned short* o = ax + (size_t)r * 320;
    if (act) {
        ushort4 ov;
        ov.x = f2bf((a0.x + a1.x) * w);
        ov.y = f2bf((a0.y + a1.y) * w);
        ov.z = f2bf((a0.z + a1.z) * w);
        ov.w = f2bf((a0.w + a1.w) * w);
        *(ushort4*)(o + t * 4) = ov;
    } else if (t < 80) {                      // zero pad cols 300..319
        ushort4 z = {0, 0, 0, 0};
        *(ushort4*)(o + t * 4) = z;
    }
}

// ---------------- bf16 MFMA GEMM: C[M][N] = A[M][lda] @ BT[N][ldb]^T  (m97-style 128x128x32) ----------------
// Grid: (N/128, M/128) -- blockIdx.x (FAST) = column tile, so consecutive blocks
// share one A-tile (L2-resident) and sweep B (L3-resident); A read ~once from HBM.
// EPI 1: bf16(leaky(acc+bias)) -> ushort C.   EPI 2: fp8(32*acc) -> uchar C.

template <int EPI>
__global__ __launch_bounds__(256) void k_mfma_gemm(const unsigned short* __restrict__ A, int lda,
                                                   const unsigned short* __restrict__ BT, int ldb,
                                                   const float* __restrict__ bias,
                                                   void* __restrict__ Cv,
                                                   int M, int N, int K) {
    __shared__ __align__(16) unsigned short As[128 * 32];
    __shared__ __align__(16) unsigned short Bs[128 * 32];
    int tid = threadIdx.x;
    int lane = tid & 63;
    int wid = tid >> 6;
    int wm = wid >> 1, wn = wid & 1;                 // 2x2 waves, 64x64 each
    int bm = blockIdx.y * 128, bn = blockIdx.x * 128;   // x = column tile (fast)

    f32x4 zero4 = {0.f, 0.f, 0.f, 0.f};
    f32x4 acc[4][4];
    #pragma unroll
    for (int i = 0; i < 4; ++i)
        #pragma unroll
        for (int j = 0; j < 4; ++j) acc[i][j] = zero4;

    int srow = tid >> 2;                // 0..63
    int scol = (tid & 3) * 8;           // k-elem offset (16B)
    int ar0 = bm + srow;      if (ar0 >= M) ar0 = M - 1;
    int ar1 = bm + srow + 64; if (ar1 >= M) ar1 = M - 1;
    const unsigned short* gA0 = A + (size_t)ar0 * lda + scol;
    const unsigned short* gA1 = A + (size_t)ar1 * lda + scol;
    const unsigned short* gB0 = BT + (size_t)(bn + srow) * ldb + scol;
    const unsigned short* gB1 = BT + (size_t)(bn + srow + 64) * ldb + scol;

    int kq = (lane >> 4) * 8;           // k-slice within tile: 0/8/16/24
    int rsel = lane & 15;

    for (int k0 = 0; k0 < K; k0 += 32) {
        gload16(gA0 + k0, &As[(size_t)tid * 8]);
        gload16(gA1 + k0, &As[(size_t)(tid + 256) * 8]);
        gload16(gB0 + k0, &Bs[(size_t)tid * 8]);
        gload16(gB1 + k0, &Bs[(size_t)(tid + 256) * 8]);
        __syncthreads();

        bf16x8 af[4], bfr[4];
        #pragma unroll
        for (int i = 0; i < 4; ++i) {
            af[i]  = *(const bf16x8*)&As[(wm * 64 + i * 16 + rsel) * 32 + kq];
            bfr[i] = *(const bf16x8*)&Bs[(wn * 64 + i * 16 + rsel) * 32 + kq];
        }
        #pragma unroll
        for (int i = 0; i < 4; ++i)
            #pragma unroll
            for (int j = 0; j < 4; ++j)
                acc[i][j] = __builtin_amdgcn_mfma_f32_16x16x32_bf16(af[i], bfr[j], acc[i][j], 0, 0, 0);
        __syncthreads();
    }

    // C/D layout (m89-verified): col = lane&15, row = (lane>>4)*4 + reg
    #pragma unroll
    for (int i = 0; i < 4; ++i) {
        int row_base = bm + wm * 64 + i * 16 + (lane >> 4) * 4;
        #pragma unroll
        for (int j = 0; j < 4; ++j) {
            int colg = bn + wn * 64 + j * 16 + (lane & 15);
            float bv = (EPI == 1) ? bias[colg] : 0.0f;
            #pragma unroll
            for (int r = 0; r < 4; ++r) {
                int row = row_base + r;
                if (row < M) {
                    float v = acc[i][j][r];
                    if (EPI == 1) {
                        v += bv; v = (v >= 0.f) ? v : 0.2f * v;
                        ((unsigned short*)Cv)[(size_t)row * N + colg] = f2bf(v);
                    } else {
                        ((unsigned char*)Cv)[(size_t)row * N + colg] = f2fp8(v * 32.0f);
                    }
                }
            }
        }
    }
}

// ---------------- SpMM2 (fp8 H2, x32-scaled) + bias + row L2 normalize ----------------

__global__ __launch_bounds__(256) void k_spmm2_norm(const int* __restrict__ ptr, const int* __restrict__ col,
                                                    const unsigned char* __restrict__ H2,
                                                    const float* __restrict__ b2,
                                                    float* __restrict__ out) {
    const int C = 2048;
    int r = blockIdx.x, t = threadIdx.x;
    int s = ptr[r], e = ptr[r + 1];
    float ac0[8] = {}, ac1[8] = {}, ac2[8] = {}, ac3[8] = {};
    const uint2* base = (const uint2*)(H2 + t * 8);   // row stride = 2048 B = 256 uint2
    int p = s;
    for (; p + 3 < e; p += 4) {
        uint2 w0 = base[(size_t)col[p]     * 256];
        uint2 w1 = base[(size_t)col[p + 1] * 256];
        uint2 w2 = base[(size_t)col[p + 2] * 256];
        uint2 w3 = base[(size_t)col[p + 3] * 256];
        ACC8(ac0, w0); ACC8(ac1, w1); ACC8(ac2, w2); ACC8(ac3, w3);
    }
    for (; p < e; ++p) {
        uint2 w = base[(size_t)col[p] * 256];
        ACC8(ac0, w);
    }
    float w = 1.0f / (32.0f * fmaxf((float)(e - s), 1.0f));   // undo x32 fp8 scale + degree avg
    float ss = 0.f;
    float vv[8];
    #pragma unroll
    for (int j = 0; j < 8; ++j) {
        float v = (ac0[j] + ac1[j] + ac2[j] + ac3[j]) * w + b2[t * 8 + j];
        vv[j] = v;
        ss += v * v;
    }
    __shared__ float red[4];
    __shared__ float scale_s;
    #pragma unroll
    for (int off = 32; off > 0; off >>= 1) ss += __shfl_down(ss, off, 64);
    int lane = t & 63, wid = t >> 6;
    if (lane == 0) red[wid] = ss;
    __syncthreads();
    if (t == 0) {
        float tot = red[0] + red[1] + red[2] + red[3];
        scale_s = 1.0f / fmaxf(sqrtf(tot), 1e-12f);
    }
    __syncthreads();
    float sc = scale_s;
    float* o = out + (size_t)r * C + t * 8;
    float4 o0 = {vv[0] * sc, vv[1] * sc, vv[2] * sc, vv[3] * sc};
    float4 o1 = {vv[4] * sc, vv[5] * sc, vv[6] * sc, vv[7] * sc};
    *(float4*)o = o0;
    *(float4*)(o + 4) = o1;
}

// ---------------- launch ----------------

extern "C" void kernel_launch(void* const* d_in, const int* in_sizes, int n_in,
                              void* d_out, int out_size, void* d_ws, size_t ws_size,
                              hipStream_t stream) {
    const float* x  = (const float*)d_in[0];
    const float* W1 = (const float*)d_in[1];
    const float* b1 = (const float*)d_in[2];
    const float* W2 = (const float*)d_in[3];
    const float* b2 = (const float*)d_in[4];
    const int* erow = (const int*)d_in[5];
    const int* ecol = (const int*)d_in[6];

    const int chid = in_sizes[2];              // 2048
    const int cout = in_sizes[4];              // 2048
    const int cin  = in_sizes[1] / chid;       // 300
    const int n    = in_sizes[0] / cin;        // 50000
    const int e    = in_sizes[5];              // 1600000
    const int cinp = (cin + 31) & ~31;         // 320 (K-pad for MFMA)
    const int nb   = (n + 1023) / 1024;        // scan blocks (49)

    char* ws = (char*)d_ws;
    size_t off = 0;
    auto alloc = [&](size_t bytes) -> void* {
        void* p = ws + off;
        off += (bytes + 255) & ~(size_t)255;
        return p;
    };
    int*            deg     = (int*)alloc((size_t)n * 4);
    int*            ptr     = (int*)alloc((size_t)(n + 1) * 4);
    int*            cursor  = (int*)alloc((size_t)n * 4);
    int*            incl    = (int*)alloc((size_t)n * 4);
    int*            bsum    = (int*)alloc((size_t)nb * 4);
    int*            boff    = (int*)alloc((size_t)nb * 4);
    int*            csr_col = (int*)alloc((size_t)e * 4);
    unsigned short* ax      = (unsigned short*)alloc((size_t)n * cinp * 2);
    unsigned short* W1T     = (unsigned short*)alloc((size_t)chid * cinp * 2);
    unsigned short* W2T     = (unsigned short*)alloc((size_t)cout * chid * 2);
    unsigned char*  H2f8    = (unsigned char*)alloc((size_t)n * cout);
    unsigned short* H1      = (unsigned short*)d_out;   // bf16 H1 stashed in d_out; fully overwritten at the end

    k_zero_i32<<<(n + 255) / 256, 256, 0, stream>>>(deg, n);
    k_count_deg<<<2048, 256, 0, stream>>>(erow, deg, e);
    k_scan1<<<nb, 1024, 0, stream>>>(deg, incl, bsum, n);
    k_scan2<<<1, 64, 0, stream>>>(bsum, boff, nb);
    k_scan3<<<nb, 1024, 0, stream>>>(deg, incl, boff, ptr, cursor, n);
    k_scatter<<<2048, 256, 0, stream>>>(erow, ecol, cursor, csr_col, e);

    dim3 gw1(cinp / 32, chid / 32);
    k_cvt_wT<<<gw1, 256, 0, stream>>>(W1, W1T, cin, chid, cinp);
    dim3 gw2(chid / 32, cout / 32);
    k_cvt_wT<<<gw2, 256, 0, stream>>>(W2, W2T, chid, cout, chid);

    k_spmm1<<<n, 128, 0, stream>>>(ptr, csr_col, x, ax);

    dim3 g1(chid / 128, (n + 127) / 128);   // x = column tile (fast) for A-reuse
    // H1 = bf16(LeakyReLU((A@X)bf16 @ W1 + b1))
    k_mfma_gemm<1><<<g1, 256, 0, stream>>>(ax, cinp, W1T, cinp, b1, (void*)H1, n, chid, cinp);

    dim3 g2(cout / 128, (n + 127) / 128);   // x = column tile (fast)
    // H2 = fp8(32 * (H1 @ W2))
    k_mfma_gemm<2><<<g2, 256, 0, stream>>>(H1, chid, W2T, chid, (const float*)nullptr, (void*)H2f8, n, cout, chid);

    // out = normalize(A @ H2 + b2)
    k_spmm2_norm<<<n, 256, 0, stream>>>(ptr, csr_col, H2f8, b2, (float*)d_out);
}